// Round 7
// baseline (57269.989 us; speedup 1.0000x reference)
//
#include <hip/hip_runtime.h>
#include <hip/hip_bf16.h>

typedef __attribute__((ext_vector_type(4))) float f32x4;
typedef __attribute__((ext_vector_type(8))) short bf16x8;
typedef unsigned short u16;

#define DEV static __device__ __forceinline__

DEV u16 f2bf(float f){
  unsigned v = __float_as_uint(f);
  v += 0x7fffu + ((v >> 16) & 1u);
  return (u16)(v >> 16);
}
DEV float bf2f(u16 u){ return __uint_as_float(((unsigned)u) << 16); }
DEV float sigm(float x){ return 1.0f / (1.0f + __expf(-x)); }
DEV float tanh_(float x){ return 1.0f - 2.0f / (__expf(2.0f * x) + 1.0f); }
DEV bf16x8 ld8(const u16* p){ return *(const bf16x8*)p; }
DEV float clip6(float v){ return fminf(fmaxf(v, -6.f), 6.f); }

template<int KIT, int NT>
DEV void mmK(const u16* ap, const u16* wp, int ldw, f32x4* acc){
  #pragma unroll 4
  for (int kk = 0; kk < KIT; ++kk){
    bf16x8 a = ld8(ap + kk * 32);
    #pragma unroll
    for (int nt = 0; nt < NT; ++nt){
      bf16x8 b = ld8(wp + (size_t)(nt * 16) * ldw + kk * 32);
      acc[nt] = __builtin_amdgcn_mfma_f32_16x16x32_bf16(a, b, acc[nt], 0, 0, 0);
    }
  }
}

// ---------------- prologue kernels (convert + phi_x precompute) ----------------
struct GemmDesc {
  const u16* A; const u16* W; const float* bias; u16* out;
  int lda, ldw, ldo, N, K;
};

__global__ __launch_bounds__(256) void k_gemm_pre(GemmDesc d){
  const int ntn = d.N >> 6;
  const int bm = blockIdx.x / ntn, bn = blockIdx.x - bm * ntn;
  const int w = threadIdx.x >> 6, lane = threadIdx.x & 63;
  const int r = lane & 15, g = lane >> 4;
  const int m0 = bm * 64 + w * 16, n0 = bn * 64;
  f32x4 acc[4];
  #pragma unroll
  for (int i = 0; i < 4; ++i) acc[i] = (f32x4){0.f, 0.f, 0.f, 0.f};
  const u16* ap = d.A + (size_t)(m0 + r) * d.lda + g * 8;
  const u16* wp = d.W + (size_t)(n0 + r) * d.ldw + g * 8;
  for (int k = 0; k < d.K; k += 32){
    bf16x8 a = ld8(ap + k);
    #pragma unroll
    for (int nt = 0; nt < 4; ++nt){
      bf16x8 b = ld8(wp + (size_t)(nt * 16) * d.ldw + k);
      acc[nt] = __builtin_amdgcn_mfma_f32_16x16x32_bf16(a, b, acc[nt], 0, 0, 0);
    }
  }
  #pragma unroll
  for (int nt = 0; nt < 4; ++nt)
    #pragma unroll
    for (int i = 0; i < 4; ++i){
      const int row = m0 + g * 4 + i, col = n0 + nt * 16 + r;
      float v = fmaxf(acc[nt][i] + d.bias[col], 0.f);
      d.out[(size_t)row * d.ldo + col] = f2bf(v);
    }
}

#define NCONV 19
struct ConvMulti { const float* src[NCONV]; u16* dst[NCONV]; int n[NCONV]; int total; };

__global__ __launch_bounds__(256) void k_convert(ConvMulti cm){
  const int stride = gridDim.x * blockDim.x;
  for (int i = blockIdx.x * blockDim.x + threadIdx.x; i < cm.total; i += stride){
    int idx = i, di = 0;
    while (idx >= cm.n[di]){ idx -= cm.n[di]; ++di; }
    cm.dst[di][idx] = f2bf(cm.src[di][idx]);
  }
}

// ---------------- the per-row-group full-recurrence kernel ----------------
// 16 blocks x 1024 threads (16 waves = 4 waves/SIMD for latency hiding).
// Block b owns batch rows [16b, 16b+16) for ALL 128 steps. Wave w owns a
// 32-col slice c0 = w*32 of every 512-wide GEMM. No cross-block comms.
struct Params {
  const u16 *phiX, *e1, *pr, *e2, *emu, *elv, *pmu, *plv, *pz, *d1, *ih0, *hh0, *ih1, *hh1, *d2, *dmu, *dlv;
  const float *b_e1, *b_pr, *b_e2, *b_emu, *b_elv, *b_pmu, *b_plv, *b_pz, *b_d1, *b_d2, *b_dmu, *b_dlv;
  const float *eps, *x;
  u16 *h0a, *h0b, *h1a, *h1b;
  float *accf; // [0..15] per-block KL, [16..31] per-block NLL
};

#define HP 520  // LDS row pitch in u16

__global__ __launch_bounds__(1024) void k_vrnn16(Params P)
{
  const int tid = threadIdx.x, w = tid >> 6, lane = tid & 63;
  const int r = lane & 15, g = lane >> 4;
  const int bid = blockIdx.x, m0 = bid * 16;
  const int c0 = w * 32;

  __shared__ u16 ench1_s[16 * HP], prih_s[16 * HP], phiz_s[16 * HP], dech1_s[16 * HP], dh_s[16 * HP];
  __shared__ float fbuf[4096];
  __shared__ u16 zs[16 * 72];
  __shared__ float red[1024];
  float* qmu_s = fbuf;        float* qlv_s = fbuf + 1024;
  float* pmu_s = fbuf + 2048; float* plv_s = fbuf + 3072;
  float* dmu_s = fbuf;        float* dlv_s = fbuf + 2048; // time-disjoint alias

  float klacc = 0.f, nllacc = 0.f;

  for (int t = 0; t < 128; ++t){
    const u16* h1o = (t & 1) ? P.h1b : P.h1a;  u16* h1n = (t & 1) ? P.h1a : P.h1b;
    const u16* h0o = (t & 1) ? P.h0b : P.h0a;  u16* h0n = (t & 1) ? P.h0a : P.h0b;
    const u16* aX  = P.phiX + ((size_t)t * 256 + m0 + r) * 512 + g * 8;
    const u16* aH1 = h1o + (size_t)(m0 + r) * 512 + g * 8;
    const u16* aH0 = h0o + (size_t)(m0 + r) * 512 + g * 8;

    // P1: ench1 = relu([phiX_t | h1] @ e1^T + b) : wave cols c0..c0+32
    { f32x4 acc[2] = {(f32x4){0,0,0,0},(f32x4){0,0,0,0}};
      mmK<16,2>(aX,  P.e1 + (size_t)(c0 + r) * 1024 + g * 8, 1024, acc);
      mmK<16,2>(aH1, P.e1 + (size_t)(c0 + r) * 1024 + 512 + g * 8, 1024, acc);
      #pragma unroll
      for (int nt = 0; nt < 2; ++nt)
        #pragma unroll
        for (int i = 0; i < 4; ++i){
          const int row = g * 4 + i, col = c0 + nt * 16 + r;
          ench1_s[row * HP + col] = f2bf(fmaxf(acc[nt][i] + P.b_e1[col], 0.f));
        }
    }
    // P2: prih = relu(h1 @ pr^T + b)
    { f32x4 acc[2] = {(f32x4){0,0,0,0},(f32x4){0,0,0,0}};
      mmK<16,2>(aH1, P.pr + (size_t)(c0 + r) * 512 + g * 8, 512, acc);
      #pragma unroll
      for (int nt = 0; nt < 2; ++nt)
        #pragma unroll
        for (int i = 0; i < 4; ++i){
          const int row = g * 4 + i, col = c0 + nt * 16 + r;
          prih_s[row * HP + col] = f2bf(fmaxf(acc[nt][i] + P.b_pr[col], 0.f));
        }
    }
    __syncthreads();
    // P3: ench = relu(ench1 @ e2^T + b) -> dh_s
    { f32x4 acc[2] = {(f32x4){0,0,0,0},(f32x4){0,0,0,0}};
      mmK<16,2>(ench1_s + r * HP + g * 8, P.e2 + (size_t)(c0 + r) * 512 + g * 8, 512, acc);
      #pragma unroll
      for (int nt = 0; nt < 2; ++nt)
        #pragma unroll
        for (int i = 0; i < 4; ++i){
          const int row = g * 4 + i, col = c0 + nt * 16 + r;
          dh_s[row * HP + col] = f2bf(fmaxf(acc[nt][i] + P.b_e2[col], 0.f));
        }
    }
    __syncthreads();
    // P4: heads: wave w -> head (w>>2) in {qmu,qlv,pmu,plv}, cols (w&3)*16
    { f32x4 acc[1] = {(f32x4){0,0,0,0}};
      const int hd = w >> 2, cc = (w & 3) * 16;
      const u16* A  = (hd < 2) ? dh_s : prih_s;
      const u16* W_ = (hd == 0) ? P.emu : (hd == 1) ? P.elv : (hd == 2) ? P.pmu : P.plv;
      const float* bs = (hd == 0) ? P.b_emu : (hd == 1) ? P.b_elv : (hd == 2) ? P.b_pmu : P.b_plv;
      float* outp = (hd == 0) ? qmu_s : (hd == 1) ? qlv_s : (hd == 2) ? pmu_s : plv_s;
      const bool cl = (hd & 1);
      mmK<16,1>(A + r * HP + g * 8, W_ + (size_t)(cc + r) * 512 + g * 8, 512, acc);
      #pragma unroll
      for (int i = 0; i < 4; ++i){
        const int row = g * 4 + i, col = cc + r;
        float v = acc[0][i] + bs[col];
        if (cl) v = clip6(v);
        outp[row * 64 + col] = v;
      }
    }
    __syncthreads();
    // z + KL accumulate: one element per thread
    { const float* epst = P.eps + (size_t)t * 16384 + (size_t)m0 * 64;
      const int e = tid, row = e >> 6, col = e & 63;
      const float qm = qmu_s[e], qv = qlv_s[e];
      const float pm = pmu_s[e], pv = plv_s[e];
      const float zv = qm + epst[row * 64 + col] * __expf(0.5f * qv);
      zs[row * 72 + col] = f2bf(zv);
      const float dm = qm - pm;
      klacc += 0.5f * (pv - qv + (__expf(qv) + dm * dm) * __expf(-pv) - 1.f);
    }
    __syncthreads();
    // phiz = relu(z @ pz^T + b)
    { f32x4 acc[2] = {(f32x4){0,0,0,0},(f32x4){0,0,0,0}};
      mmK<2,2>(zs + r * 72 + g * 8, P.pz + (size_t)(c0 + r) * 64 + g * 8, 64, acc);
      #pragma unroll
      for (int nt = 0; nt < 2; ++nt)
        #pragma unroll
        for (int i = 0; i < 4; ++i){
          const int row = g * 4 + i, col = c0 + nt * 16 + r;
          phiz_s[row * HP + col] = f2bf(fmaxf(acc[nt][i] + P.b_pz[col], 0.f));
        }
    }
    __syncthreads();
    // P5: dech1 = relu([phiz | h1] @ d1^T + b)
    { f32x4 acc[2] = {(f32x4){0,0,0,0},(f32x4){0,0,0,0}};
      mmK<16,2>(phiz_s + r * HP + g * 8, P.d1 + (size_t)(c0 + r) * 1024 + g * 8, 1024, acc);
      mmK<16,2>(aH1, P.d1 + (size_t)(c0 + r) * 1024 + 512 + g * 8, 1024, acc);
      #pragma unroll
      for (int nt = 0; nt < 2; ++nt)
        #pragma unroll
        for (int i = 0; i < 4; ++i){
          const int row = g * 4 + i, col = c0 + nt * 16 + r;
          dech1_s[row * HP + col] = f2bf(fmaxf(acc[nt][i] + P.b_d1[col], 0.f));
        }
    }
    // P6: GRU0: gi0 = [phiX_t | phiz] @ ih0^T, gh0 = h0 @ hh0^T, combine -> h0n (cols c0..+32)
    { const u16* aZ = phiz_s + r * HP + g * 8;
      f32x4 gi[3][2], gh[3][2];
      #pragma unroll
      for (int gt = 0; gt < 3; ++gt)
        #pragma unroll
        for (int i = 0; i < 2; ++i){ gi[gt][i] = (f32x4){0,0,0,0}; gh[gt][i] = (f32x4){0,0,0,0}; }
      #pragma unroll
      for (int gt = 0; gt < 3; ++gt){
        const u16* wih = P.ih0 + (size_t)(gt * 512 + c0 + r) * 1024 + g * 8;
        mmK<16,2>(aX, wih, 1024, gi[gt]);
        mmK<16,2>(aZ, wih + 512, 1024, gi[gt]);
        mmK<16,2>(aH0, P.hh0 + (size_t)(gt * 512 + c0 + r) * 512 + g * 8, 512, gh[gt]);
      }
      #pragma unroll
      for (int nt = 0; nt < 2; ++nt)
        #pragma unroll
        for (int i = 0; i < 4; ++i){
          const int row = g * 4 + i, c = c0 + nt * 16 + r;
          const float rr = sigm(gi[0][nt][i] + gh[0][nt][i]);
          const float zg = sigm(gi[1][nt][i] + gh[1][nt][i]);
          const float nn = tanh_(gi[2][nt][i] + rr * gh[2][nt][i]);
          const float hv = (1.f - zg) * nn + zg * bf2f(h0o[(size_t)(m0 + row) * 512 + c]);
          h0n[(size_t)(m0 + row) * 512 + c] = f2bf(hv);
        }
    }
    __syncthreads();  // h0n visible (same CU; vmcnt drained at barrier)
    // P7: GRU1: gi1 = h0n @ ih1^T, gh1 = h1 @ hh1^T, combine -> h1n
    { const u16* aH0n = h0n + (size_t)(m0 + r) * 512 + g * 8;
      f32x4 gi[3][2], gh[3][2];
      #pragma unroll
      for (int gt = 0; gt < 3; ++gt)
        #pragma unroll
        for (int i = 0; i < 2; ++i){ gi[gt][i] = (f32x4){0,0,0,0}; gh[gt][i] = (f32x4){0,0,0,0}; }
      #pragma unroll
      for (int gt = 0; gt < 3; ++gt){
        mmK<16,2>(aH0n, P.ih1 + (size_t)(gt * 512 + c0 + r) * 512 + g * 8, 512, gi[gt]);
        mmK<16,2>(aH1,  P.hh1 + (size_t)(gt * 512 + c0 + r) * 512 + g * 8, 512, gh[gt]);
      }
      #pragma unroll
      for (int nt = 0; nt < 2; ++nt)
        #pragma unroll
        for (int i = 0; i < 4; ++i){
          const int row = g * 4 + i, c = c0 + nt * 16 + r;
          const float rr = sigm(gi[0][nt][i] + gh[0][nt][i]);
          const float zg = sigm(gi[1][nt][i] + gh[1][nt][i]);
          const float nn = tanh_(gi[2][nt][i] + rr * gh[2][nt][i]);
          const float hv = (1.f - zg) * nn + zg * bf2f(h1o[(size_t)(m0 + row) * 512 + c]);
          h1n[(size_t)(m0 + row) * 512 + c] = f2bf(hv);
        }
    }
    __syncthreads();
    // P8: dech = relu(dech1 @ d2^T + b) -> dh_s (reuse)
    { f32x4 acc[2] = {(f32x4){0,0,0,0},(f32x4){0,0,0,0}};
      mmK<16,2>(dech1_s + r * HP + g * 8, P.d2 + (size_t)(c0 + r) * 512 + g * 8, 512, acc);
      #pragma unroll
      for (int nt = 0; nt < 2; ++nt)
        #pragma unroll
        for (int i = 0; i < 4; ++i){
          const int row = g * 4 + i, col = c0 + nt * 16 + r;
          dh_s[row * HP + col] = f2bf(fmaxf(acc[nt][i] + P.b_d2[col], 0.f));
        }
    }
    __syncthreads();
    // dec heads: wave w -> (w<8 ? dmu : dlv), cols (w&7)*16 of 128
    { f32x4 acc[1] = {(f32x4){0,0,0,0}};
      const bool isLv = (w >= 8); const int cc = (w & 7) * 16;
      const u16* W_ = isLv ? P.dlv : P.dmu;
      const float* bs = isLv ? P.b_dlv : P.b_dmu;
      mmK<16,1>(dh_s + r * HP + g * 8, W_ + (size_t)(cc + r) * 512 + g * 8, 512, acc);
      #pragma unroll
      for (int i = 0; i < 4; ++i){
        const int row = g * 4 + i, col = cc + r;
        float v = acc[0][i] + bs[col];
        if (isLv) v = clip6(v);
        (isLv ? dlv_s : dmu_s)[row * 128 + col] = v;
      }
    }
    __syncthreads();
    // NLL accumulate: 2048 elements over 1024 threads
    { const float* xt = P.x + (size_t)t * 32768 + (size_t)m0 * 128;
      #pragma unroll
      for (int q = 0; q < 2; ++q){
        const int e = tid + q * 1024, row = e >> 7, col = e & 127;
        const float mu = dmu_s[e], lv = dlv_s[e];
        const float d = xt[row * 128 + col] - mu;
        nllacc += 0.5f * (lv + d * d * __expf(-lv));
      }
    }
    __syncthreads();
  }

  // per-block reductions -> plain stores (deterministic, no atomics)
  red[tid] = klacc;
  __syncthreads();
  for (int s = 512; s > 0; s >>= 1){ if (tid < s) red[tid] += red[tid + s]; __syncthreads(); }
  if (tid == 0) P.accf[bid] = red[0];
  __syncthreads();
  red[tid] = nllacc;
  __syncthreads();
  for (int s = 512; s > 0; s >>= 1){ if (tid < s) red[tid] += red[tid + s]; __syncthreads(); }
  if (tid == 0) P.accf[16 + bid] = red[0];
}

__global__ void k_final(const float* __restrict__ accf, float* __restrict__ out){
  if (threadIdx.x == 0 && blockIdx.x == 0){
    float kl = 0.f, rc = 0.f;
    for (int i = 0; i < 16; ++i){ kl += accf[i]; rc += accf[16 + i]; }
    kl *= (1.f / 32768.f);  // / B / T
    rc *= (1.f / 32768.f);
    out[0] = rc + kl; out[1] = rc; out[2] = kl;
  }
}

extern "C" void kernel_launch(void* const* d_in, const int* in_sizes, int n_in,
                              void* d_out, int out_size, void* d_ws, size_t ws_size,
                              hipStream_t stream)
{
  (void)in_sizes; (void)n_in; (void)out_size; (void)ws_size;
  const float* x     = (const float*)d_in[0];
  const float* eps   = (const float*)d_in[1];
  const float* w_px1 = (const float*)d_in[2];
  const float* b_px1 = (const float*)d_in[3];
  const float* w_px2 = (const float*)d_in[4];
  const float* b_px2 = (const float*)d_in[5];
  const float* w_pz  = (const float*)d_in[6];
  const float* b_pz  = (const float*)d_in[7];
  const float* w_e1  = (const float*)d_in[8];
  const float* b_e1  = (const float*)d_in[9];
  const float* w_e2  = (const float*)d_in[10];
  const float* b_e2  = (const float*)d_in[11];
  const float* w_emu = (const float*)d_in[12];
  const float* b_emu = (const float*)d_in[13];
  const float* w_elv = (const float*)d_in[14];
  const float* b_elv = (const float*)d_in[15];
  const float* w_pr  = (const float*)d_in[16];
  const float* b_pr  = (const float*)d_in[17];
  const float* w_pmu = (const float*)d_in[18];
  const float* b_pmu = (const float*)d_in[19];
  const float* w_plv = (const float*)d_in[20];
  const float* b_plv = (const float*)d_in[21];
  const float* w_d1  = (const float*)d_in[22];
  const float* b_d1  = (const float*)d_in[23];
  const float* w_d2  = (const float*)d_in[24];
  const float* b_d2  = (const float*)d_in[25];
  const float* w_dmu = (const float*)d_in[26];
  const float* b_dmu = (const float*)d_in[27];
  const float* w_dlv = (const float*)d_in[28];
  const float* b_dlv = (const float*)d_in[29];
  const float* w_ih0 = (const float*)d_in[30];
  const float* w_hh0 = (const float*)d_in[31];
  const float* w_ih1 = (const float*)d_in[32];
  const float* w_hh1 = (const float*)d_in[33];

  char* base = (char*)d_ws;
  size_t off = 0;
  auto alloc = [&](size_t bytes)->char*{
    char* p = base + off;
    off = (off + bytes + 255) & ~(size_t)255;
    return p;
  };
  u16* xbf    = (u16*)alloc((size_t)4194304 * 2);
  u16* cb_px1 = (u16*)alloc((size_t)65536 * 2);
  u16* cb_px2 = (u16*)alloc((size_t)262144 * 2);
  u16* cb_pz  = (u16*)alloc((size_t)32768 * 2);
  u16* cb_e1  = (u16*)alloc((size_t)524288 * 2);
  u16* cb_e2  = (u16*)alloc((size_t)262144 * 2);
  u16* cb_emu = (u16*)alloc((size_t)32768 * 2);
  u16* cb_elv = (u16*)alloc((size_t)32768 * 2);
  u16* cb_pr  = (u16*)alloc((size_t)262144 * 2);
  u16* cb_pmu = (u16*)alloc((size_t)32768 * 2);
  u16* cb_plv = (u16*)alloc((size_t)32768 * 2);
  u16* cb_d1  = (u16*)alloc((size_t)524288 * 2);
  u16* cb_d2  = (u16*)alloc((size_t)262144 * 2);
  u16* cb_dmu = (u16*)alloc((size_t)65536 * 2);
  u16* cb_dlv = (u16*)alloc((size_t)65536 * 2);
  u16* cb_ih0 = (u16*)alloc((size_t)1572864 * 2);
  u16* cb_hh0 = (u16*)alloc((size_t)786432 * 2);
  u16* cb_ih1 = (u16*)alloc((size_t)786432 * 2);
  u16* cb_hh1 = (u16*)alloc((size_t)786432 * 2);
  u16* phiX   = (u16*)alloc((size_t)16777216 * 2);
  u16* phiX1  = (u16*)alloc((size_t)16777216 * 2);
  u16* h0a = (u16*)alloc((size_t)131072 * 2);
  u16* h0b = (u16*)alloc((size_t)131072 * 2);
  u16* h1a = (u16*)alloc((size_t)131072 * 2);
  u16* h1b = (u16*)alloc((size_t)131072 * 2);
  float* accf = (float*)alloc(256);

  // zero h state (4 contiguous buffers of 262144 B each)
  hipMemsetAsync(h0a, 0, (size_t)4 * 262144, stream);

  // convert x + weights to bf16
  ConvMulti cm; int ci = 0, tot = 0;
  auto addc = [&](const float* s, u16* d, int n){ cm.src[ci] = s; cm.dst[ci] = d; cm.n[ci] = n; ++ci; tot += n; };
  addc(x, xbf, 4194304);
  addc(w_px1, cb_px1, 65536);   addc(w_px2, cb_px2, 262144);
  addc(w_pz,  cb_pz,  32768);   addc(w_e1,  cb_e1,  524288);
  addc(w_e2,  cb_e2,  262144);  addc(w_emu, cb_emu, 32768);
  addc(w_elv, cb_elv, 32768);   addc(w_pr,  cb_pr,  262144);
  addc(w_pmu, cb_pmu, 32768);   addc(w_plv, cb_plv, 32768);
  addc(w_d1,  cb_d1,  524288);  addc(w_d2,  cb_d2,  262144);
  addc(w_dmu, cb_dmu, 65536);   addc(w_dlv, cb_dlv, 65536);
  addc(w_ih0, cb_ih0, 1572864); addc(w_hh0, cb_hh0, 786432);
  addc(w_ih1, cb_ih1, 786432);  addc(w_hh1, cb_hh1, 786432);
  cm.total = tot;
  k_convert<<<2048, 256, 0, stream>>>(cm);

  { // precompute phi_x over all T*B rows
    GemmDesc d1g;
    d1g.A = xbf; d1g.W = cb_px1; d1g.bias = b_px1; d1g.out = phiX1;
    d1g.lda = 128; d1g.ldw = 128; d1g.ldo = 512; d1g.N = 512; d1g.K = 128;
    k_gemm_pre<<<512 * 8, 256, 0, stream>>>(d1g);
    GemmDesc d2g;
    d2g.A = phiX1; d2g.W = cb_px2; d2g.bias = b_px2; d2g.out = phiX;
    d2g.lda = 512; d2g.ldw = 512; d2g.ldo = 512; d2g.N = 512; d2g.K = 512;
    k_gemm_pre<<<512 * 8, 256, 0, stream>>>(d2g);
  }

  Params prm;
  prm.phiX = phiX;
  prm.e1 = cb_e1; prm.pr = cb_pr; prm.e2 = cb_e2;
  prm.emu = cb_emu; prm.elv = cb_elv; prm.pmu = cb_pmu; prm.plv = cb_plv;
  prm.pz = cb_pz; prm.d1 = cb_d1; prm.ih0 = cb_ih0; prm.hh0 = cb_hh0;
  prm.ih1 = cb_ih1; prm.hh1 = cb_hh1; prm.d2 = cb_d2;
  prm.dmu = cb_dmu; prm.dlv = cb_dlv;
  prm.b_e1 = b_e1; prm.b_pr = b_pr; prm.b_e2 = b_e2;
  prm.b_emu = b_emu; prm.b_elv = b_elv; prm.b_pmu = b_pmu; prm.b_plv = b_plv;
  prm.b_pz = b_pz; prm.b_d1 = b_d1; prm.b_d2 = b_d2;
  prm.b_dmu = b_dmu; prm.b_dlv = b_dlv;
  prm.eps = eps; prm.x = x;
  prm.h0a = h0a; prm.h0b = h0b; prm.h1a = h1a; prm.h1b = h1b;
  prm.accf = accf;

  k_vrnn16<<<dim3(16), dim3(1024), 0, stream>>>(prm);
  k_final<<<dim3(1), dim3(64), 0, stream>>>(accf, (float*)d_out);
}

// Round 8
// 32538.559 us; speedup vs baseline: 1.7601x; 1.7601x over previous
//
#include <hip/hip_runtime.h>
#include <hip/hip_bf16.h>

typedef __attribute__((ext_vector_type(4))) float f32x4;
typedef __attribute__((ext_vector_type(8))) short bf16x8;
typedef unsigned short u16;

#define DEV static __device__ __forceinline__

DEV u16 f2bf(float f){
  unsigned v = __float_as_uint(f);
  v += 0x7fffu + ((v >> 16) & 1u);
  return (u16)(v >> 16);
}
DEV float bf2f(u16 u){ return __uint_as_float(((unsigned)u) << 16); }
DEV float sigm(float x){ return 1.0f / (1.0f + __expf(-x)); }
DEV float tanh_(float x){ return 1.0f - 2.0f / (__expf(2.0f * x) + 1.0f); }
DEV bf16x8 ld8(const u16* p){ return *(const bf16x8*)p; }
DEV float clip6(float v){ return fminf(fmaxf(v, -6.f), 6.f); }

// row-major B (prologue GEMMs only)
template<int KIT, int NT>
DEV void mmK(const u16* ap, const u16* wp, int ldw, f32x4* acc){
  #pragma unroll 4
  for (int kk = 0; kk < KIT; ++kk){
    bf16x8 a = ld8(ap + kk * 32);
    #pragma unroll
    for (int nt = 0; nt < NT; ++nt){
      bf16x8 b = ld8(wp + (size_t)(nt * 16) * ldw + kk * 32);
      acc[nt] = __builtin_amdgcn_mfma_f32_16x16x32_bf16(a, b, acc[nt], 0, 0, 0);
    }
  }
}

// packed fragment-linear B: wp already includes c16-base and +lane*8.
// fragment (c16, kk) occupies 512 contiguous u16; kstride = K32*512.
template<int KIT, int NT>
DEV void mmP(const u16* ap, const u16* wp, int kstride, f32x4* acc){
  #pragma unroll 8
  for (int kk = 0; kk < KIT; ++kk){
    bf16x8 a = ld8(ap + kk * 32);
    #pragma unroll
    for (int nt = 0; nt < NT; ++nt){
      bf16x8 b = ld8(wp + nt * kstride + kk * 512);
      acc[nt] = __builtin_amdgcn_mfma_f32_16x16x32_bf16(a, b, acc[nt], 0, 0, 0);
    }
  }
}

// ---------------- prologue kernels ----------------
struct GemmDesc {
  const u16* A; const u16* W; const float* bias; u16* out;
  int lda, ldw, ldo, N, K;
};

__global__ __launch_bounds__(256) void k_gemm_pre(GemmDesc d){
  const int ntn = d.N >> 6;
  const int bm = blockIdx.x / ntn, bn = blockIdx.x - bm * ntn;
  const int w = threadIdx.x >> 6, lane = threadIdx.x & 63;
  const int r = lane & 15, g = lane >> 4;
  const int m0 = bm * 64 + w * 16, n0 = bn * 64;
  f32x4 acc[4];
  #pragma unroll
  for (int i = 0; i < 4; ++i) acc[i] = (f32x4){0.f, 0.f, 0.f, 0.f};
  const u16* ap = d.A + (size_t)(m0 + r) * d.lda + g * 8;
  const u16* wp = d.W + (size_t)(n0 + r) * d.ldw + g * 8;
  for (int k = 0; k < d.K; k += 32){
    bf16x8 a = ld8(ap + k);
    #pragma unroll
    for (int nt = 0; nt < 4; ++nt){
      bf16x8 b = ld8(wp + (size_t)(nt * 16) * d.ldw + k);
      acc[nt] = __builtin_amdgcn_mfma_f32_16x16x32_bf16(a, b, acc[nt], 0, 0, 0);
    }
  }
  #pragma unroll
  for (int nt = 0; nt < 4; ++nt)
    #pragma unroll
    for (int i = 0; i < 4; ++i){
      const int row = m0 + g * 4 + i, col = n0 + nt * 16 + r;
      float v = fmaxf(acc[nt][i] + d.bias[col], 0.f);
      d.out[(size_t)row * d.ldo + col] = f2bf(v);
    }
}

// plain fp32->bf16 convert (x, phi_x weights)
#define NCONV 3
struct ConvMulti { const float* src[NCONV]; u16* dst[NCONV]; int n[NCONV]; int total; };

__global__ __launch_bounds__(256) void k_convert(ConvMulti cm){
  const int stride = gridDim.x * blockDim.x;
  for (int i = blockIdx.x * blockDim.x + threadIdx.x; i < cm.total; i += stride){
    int idx = i, di = 0;
    while (idx >= cm.n[di]){ idx -= cm.n[di]; ++di; }
    cm.dst[di][idx] = f2bf(cm.src[di][idx]);
  }
}

// repack row-major [N][K] fp32 -> fragment-linear bf16:
// dst[((c16*K32 + kk)<<9) + ((g*16+r)<<3) + j] = src[(c16*16+r)*K + kk*32+g*8+j]
#define NREP 16
struct RepMulti { const float* src[NREP]; u16* dst[NREP]; int nk[NREP]; int K[NREP]; int lg[NREP]; int total; };

__global__ __launch_bounds__(256) void k_repack(RepMulti rm){
  const int stride = gridDim.x * blockDim.x;
  for (int i = blockIdx.x * blockDim.x + threadIdx.x; i < rm.total; i += stride){
    int gid = i, di = 0;
    while (gid >= rm.nk[di]){ gid -= rm.nk[di]; ++di; }
    const int K = rm.K[di], lg = rm.lg[di];
    const int j = gid & 7;
    const int l = (gid >> 3) & 63;
    const int q = gid >> 9;
    const int kk = q & ((1 << lg) - 1);
    const int c16 = q >> lg;
    const int r = l & 15, g = l >> 4;
    const int col = c16 * 16 + r;
    const int k = kk * 32 + g * 8 + j;
    rm.dst[di][gid] = f2bf(rm.src[di][(size_t)col * K + k]);
  }
}

// ---------------- the per-row-group full-recurrence kernel ----------------
// 16 blocks x 1024 threads. Block b owns batch rows [16b,16b+16) for all 128
// steps; wave w owns cols c0=w*32. All weights pre-packed fragment-linear ->
// every B-load is 64-lane contiguous 1KB. No cross-block communication.
struct Params {
  const u16 *phiX, *e1, *pr, *e2, *emu, *elv, *pmu, *plv, *pz, *d1, *ih0, *hh0, *ih1, *hh1, *d2, *dmu, *dlv;
  const float *b_e1, *b_pr, *b_e2, *b_emu, *b_elv, *b_pmu, *b_plv, *b_pz, *b_d1, *b_d2, *b_dmu, *b_dlv;
  const float *eps, *x;
  u16 *h0a, *h0b, *h1a, *h1b;
  float *accf; // [0..15] per-block KL, [16..31] per-block NLL
};

#define HP 520  // LDS row pitch in u16

__global__ __launch_bounds__(1024) void k_vrnn16(Params P)
{
  const int tid = threadIdx.x, w = tid >> 6, lane = tid & 63;
  const int r = lane & 15, g = lane >> 4;
  const int bid = blockIdx.x, m0 = bid * 16;
  const int c0 = w * 32;

  __shared__ u16 ench1_s[16 * HP], prih_s[16 * HP], phiz_s[16 * HP], dech1_s[16 * HP], dh_s[16 * HP];
  __shared__ float fbuf[4096];
  __shared__ u16 zs[16 * 72];
  __shared__ float red[1024];
  float* qmu_s = fbuf;        float* qlv_s = fbuf + 1024;
  float* pmu_s = fbuf + 2048; float* plv_s = fbuf + 3072;
  float* dmu_s = fbuf;        float* dlv_s = fbuf + 2048; // time-disjoint alias

  float klacc = 0.f, nllacc = 0.f;

  // packed-weight per-wave base pointers (kstride in u16: K32*512)
  const u16* Qe1 = P.e1 + (size_t)(w * 2) * 16384 + lane * 8;   // K=1024
  const u16* Qpr = P.pr + (size_t)(w * 2) * 8192 + lane * 8;    // K=512
  const u16* Qe2 = P.e2 + (size_t)(w * 2) * 8192 + lane * 8;
  const u16* Qpz = P.pz + (size_t)(w * 2) * 1024 + lane * 8;    // K=64
  const u16* Qd1 = P.d1 + (size_t)(w * 2) * 16384 + lane * 8;
  const u16* Qd2 = P.d2 + (size_t)(w * 2) * 8192 + lane * 8;
  const u16* Qhd = ((w >> 2) == 0 ? P.emu : (w >> 2) == 1 ? P.elv : (w >> 2) == 2 ? P.pmu : P.plv)
                   + (size_t)(w & 3) * 8192 + lane * 8;
  const u16* Qdh = (w < 8 ? P.dmu : P.dlv) + (size_t)(w & 7) * 8192 + lane * 8;

  for (int t = 0; t < 128; ++t){
    const u16* h1o = (t & 1) ? P.h1b : P.h1a;  u16* h1n = (t & 1) ? P.h1a : P.h1b;
    const u16* h0o = (t & 1) ? P.h0b : P.h0a;  u16* h0n = (t & 1) ? P.h0a : P.h0b;
    const u16* aX  = P.phiX + ((size_t)t * 256 + m0 + r) * 512 + g * 8;
    const u16* aH1 = h1o + (size_t)(m0 + r) * 512 + g * 8;
    const u16* aH0 = h0o + (size_t)(m0 + r) * 512 + g * 8;

    // P1: ench1 = relu([phiX_t | h1] @ e1^T + b) : wave cols c0..c0+32
    { f32x4 acc[2] = {(f32x4){0,0,0,0},(f32x4){0,0,0,0}};
      mmP<16,2>(aX,  Qe1, 16384, acc);
      mmP<16,2>(aH1, Qe1 + 8192, 16384, acc);
      #pragma unroll
      for (int nt = 0; nt < 2; ++nt)
        #pragma unroll
        for (int i = 0; i < 4; ++i){
          const int row = g * 4 + i, col = c0 + nt * 16 + r;
          ench1_s[row * HP + col] = f2bf(fmaxf(acc[nt][i] + P.b_e1[col], 0.f));
        }
    }
    // P2: prih = relu(h1 @ pr^T + b)
    { f32x4 acc[2] = {(f32x4){0,0,0,0},(f32x4){0,0,0,0}};
      mmP<16,2>(aH1, Qpr, 8192, acc);
      #pragma unroll
      for (int nt = 0; nt < 2; ++nt)
        #pragma unroll
        for (int i = 0; i < 4; ++i){
          const int row = g * 4 + i, col = c0 + nt * 16 + r;
          prih_s[row * HP + col] = f2bf(fmaxf(acc[nt][i] + P.b_pr[col], 0.f));
        }
    }
    __syncthreads();
    // P3: ench = relu(ench1 @ e2^T + b) -> dh_s
    { f32x4 acc[2] = {(f32x4){0,0,0,0},(f32x4){0,0,0,0}};
      mmP<16,2>(ench1_s + r * HP + g * 8, Qe2, 8192, acc);
      #pragma unroll
      for (int nt = 0; nt < 2; ++nt)
        #pragma unroll
        for (int i = 0; i < 4; ++i){
          const int row = g * 4 + i, col = c0 + nt * 16 + r;
          dh_s[row * HP + col] = f2bf(fmaxf(acc[nt][i] + P.b_e2[col], 0.f));
        }
    }
    __syncthreads();
    // P4: heads: wave w -> head (w>>2) in {qmu,qlv,pmu,plv}, cols (w&3)*16
    { f32x4 acc[1] = {(f32x4){0,0,0,0}};
      const int hd = w >> 2, cc = (w & 3) * 16;
      const u16* A  = (hd < 2) ? dh_s : prih_s;
      const float* bs = (hd == 0) ? P.b_emu : (hd == 1) ? P.b_elv : (hd == 2) ? P.b_pmu : P.b_plv;
      float* outp = (hd == 0) ? qmu_s : (hd == 1) ? qlv_s : (hd == 2) ? pmu_s : plv_s;
      const bool cl = (hd & 1);
      mmP<16,1>(A + r * HP + g * 8, Qhd, 8192, acc);
      #pragma unroll
      for (int i = 0; i < 4; ++i){
        const int row = g * 4 + i, col = cc + r;
        float v = acc[0][i] + bs[col];
        if (cl) v = clip6(v);
        outp[row * 64 + col] = v;
      }
    }
    __syncthreads();
    // z + KL accumulate: one element per thread
    { const float* epst = P.eps + (size_t)t * 16384 + (size_t)m0 * 64;
      const int e = tid, row = e >> 6, col = e & 63;
      const float qm = qmu_s[e], qv = qlv_s[e];
      const float pm = pmu_s[e], pv = plv_s[e];
      const float zv = qm + epst[row * 64 + col] * __expf(0.5f * qv);
      zs[row * 72 + col] = f2bf(zv);
      const float dm = qm - pm;
      klacc += 0.5f * (pv - qv + (__expf(qv) + dm * dm) * __expf(-pv) - 1.f);
    }
    __syncthreads();
    // phiz = relu(z @ pz^T + b)
    { f32x4 acc[2] = {(f32x4){0,0,0,0},(f32x4){0,0,0,0}};
      mmP<2,2>(zs + r * 72 + g * 8, Qpz, 1024, acc);
      #pragma unroll
      for (int nt = 0; nt < 2; ++nt)
        #pragma unroll
        for (int i = 0; i < 4; ++i){
          const int row = g * 4 + i, col = c0 + nt * 16 + r;
          phiz_s[row * HP + col] = f2bf(fmaxf(acc[nt][i] + P.b_pz[col], 0.f));
        }
    }
    __syncthreads();
    // P5: dech1 = relu([phiz | h1] @ d1^T + b)
    { f32x4 acc[2] = {(f32x4){0,0,0,0},(f32x4){0,0,0,0}};
      mmP<16,2>(phiz_s + r * HP + g * 8, Qd1, 16384, acc);
      mmP<16,2>(aH1, Qd1 + 8192, 16384, acc);
      #pragma unroll
      for (int nt = 0; nt < 2; ++nt)
        #pragma unroll
        for (int i = 0; i < 4; ++i){
          const int row = g * 4 + i, col = c0 + nt * 16 + r;
          dech1_s[row * HP + col] = f2bf(fmaxf(acc[nt][i] + P.b_d1[col], 0.f));
        }
    }
    // P6: GRU0: gi0 = [phiX_t | phiz] @ ih0^T, gh0 = h0 @ hh0^T, combine -> h0n
    { const u16* aZ = phiz_s + r * HP + g * 8;
      f32x4 gi[3][2], gh[3][2];
      #pragma unroll
      for (int gt = 0; gt < 3; ++gt)
        #pragma unroll
        for (int i = 0; i < 2; ++i){ gi[gt][i] = (f32x4){0,0,0,0}; gh[gt][i] = (f32x4){0,0,0,0}; }
      #pragma unroll
      for (int gt = 0; gt < 3; ++gt){
        const u16* wih = P.ih0 + (size_t)(gt * 32 + w * 2) * 16384 + lane * 8;
        mmP<16,2>(aX, wih, 16384, gi[gt]);
        mmP<16,2>(aZ, wih + 8192, 16384, gi[gt]);
        mmP<16,2>(aH0, P.hh0 + (size_t)(gt * 32 + w * 2) * 8192 + lane * 8, 8192, gh[gt]);
      }
      #pragma unroll
      for (int nt = 0; nt < 2; ++nt)
        #pragma unroll
        for (int i = 0; i < 4; ++i){
          const int row = g * 4 + i, c = c0 + nt * 16 + r;
          const float rr = sigm(gi[0][nt][i] + gh[0][nt][i]);
          const float zg = sigm(gi[1][nt][i] + gh[1][nt][i]);
          const float nn = tanh_(gi[2][nt][i] + rr * gh[2][nt][i]);
          const float hv = (1.f - zg) * nn + zg * bf2f(h0o[(size_t)(m0 + row) * 512 + c]);
          h0n[(size_t)(m0 + row) * 512 + c] = f2bf(hv);
        }
    }
    __syncthreads();  // h0n visible (same CU; vmcnt drained at barrier)
    // P7: GRU1: gi1 = h0n @ ih1^T, gh1 = h1 @ hh1^T, combine -> h1n
    { const u16* aH0n = h0n + (size_t)(m0 + r) * 512 + g * 8;
      f32x4 gi[3][2], gh[3][2];
      #pragma unroll
      for (int gt = 0; gt < 3; ++gt)
        #pragma unroll
        for (int i = 0; i < 2; ++i){ gi[gt][i] = (f32x4){0,0,0,0}; gh[gt][i] = (f32x4){0,0,0,0}; }
      #pragma unroll
      for (int gt = 0; gt < 3; ++gt){
        mmP<16,2>(aH0n, P.ih1 + (size_t)(gt * 32 + w * 2) * 8192 + lane * 8, 8192, gi[gt]);
        mmP<16,2>(aH1,  P.hh1 + (size_t)(gt * 32 + w * 2) * 8192 + lane * 8, 8192, gh[gt]);
      }
      #pragma unroll
      for (int nt = 0; nt < 2; ++nt)
        #pragma unroll
        for (int i = 0; i < 4; ++i){
          const int row = g * 4 + i, c = c0 + nt * 16 + r;
          const float rr = sigm(gi[0][nt][i] + gh[0][nt][i]);
          const float zg = sigm(gi[1][nt][i] + gh[1][nt][i]);
          const float nn = tanh_(gi[2][nt][i] + rr * gh[2][nt][i]);
          const float hv = (1.f - zg) * nn + zg * bf2f(h1o[(size_t)(m0 + row) * 512 + c]);
          h1n[(size_t)(m0 + row) * 512 + c] = f2bf(hv);
        }
    }
    __syncthreads();
    // P8: dech = relu(dech1 @ d2^T + b) -> dh_s (reuse)
    { f32x4 acc[2] = {(f32x4){0,0,0,0},(f32x4){0,0,0,0}};
      mmP<16,2>(dech1_s + r * HP + g * 8, Qd2, 8192, acc);
      #pragma unroll
      for (int nt = 0; nt < 2; ++nt)
        #pragma unroll
        for (int i = 0; i < 4; ++i){
          const int row = g * 4 + i, col = c0 + nt * 16 + r;
          dh_s[row * HP + col] = f2bf(fmaxf(acc[nt][i] + P.b_d2[col], 0.f));
        }
    }
    __syncthreads();
    // dec heads: wave w -> (w<8 ? dmu : dlv), cols (w&7)*16 of 128
    { f32x4 acc[1] = {(f32x4){0,0,0,0}};
      const bool isLv = (w >= 8); const int cc = (w & 7) * 16;
      const float* bs = isLv ? P.b_dlv : P.b_dmu;
      mmP<16,1>(dh_s + r * HP + g * 8, Qdh, 8192, acc);
      #pragma unroll
      for (int i = 0; i < 4; ++i){
        const int row = g * 4 + i, col = cc + r;
        float v = acc[0][i] + bs[col];
        if (isLv) v = clip6(v);
        (isLv ? dlv_s : dmu_s)[row * 128 + col] = v;
      }
    }
    __syncthreads();
    // NLL accumulate: 2048 elements over 1024 threads
    { const float* xt = P.x + (size_t)t * 32768 + (size_t)m0 * 128;
      #pragma unroll
      for (int q = 0; q < 2; ++q){
        const int e = tid + q * 1024, row = e >> 7, col = e & 127;
        const float mu = dmu_s[e], lv = dlv_s[e];
        const float d = xt[row * 128 + col] - mu;
        nllacc += 0.5f * (lv + d * d * __expf(-lv));
      }
    }
    __syncthreads();
  }

  // per-block reductions -> plain stores (deterministic, no atomics)
  red[tid] = klacc;
  __syncthreads();
  for (int s = 512; s > 0; s >>= 1){ if (tid < s) red[tid] += red[tid + s]; __syncthreads(); }
  if (tid == 0) P.accf[bid] = red[0];
  __syncthreads();
  red[tid] = nllacc;
  __syncthreads();
  for (int s = 512; s > 0; s >>= 1){ if (tid < s) red[tid] += red[tid + s]; __syncthreads(); }
  if (tid == 0) P.accf[16 + bid] = red[0];
}

__global__ void k_final(const float* __restrict__ accf, float* __restrict__ out){
  if (threadIdx.x == 0 && blockIdx.x == 0){
    float kl = 0.f, rc = 0.f;
    for (int i = 0; i < 16; ++i){ kl += accf[i]; rc += accf[16 + i]; }
    kl *= (1.f / 32768.f);  // / B / T
    rc *= (1.f / 32768.f);
    out[0] = rc + kl; out[1] = rc; out[2] = kl;
  }
}

extern "C" void kernel_launch(void* const* d_in, const int* in_sizes, int n_in,
                              void* d_out, int out_size, void* d_ws, size_t ws_size,
                              hipStream_t stream)
{
  (void)in_sizes; (void)n_in; (void)out_size; (void)ws_size;
  const float* x     = (const float*)d_in[0];
  const float* eps   = (const float*)d_in[1];
  const float* w_px1 = (const float*)d_in[2];
  const float* b_px1 = (const float*)d_in[3];
  const float* w_px2 = (const float*)d_in[4];
  const float* b_px2 = (const float*)d_in[5];
  const float* w_pz  = (const float*)d_in[6];
  const float* b_pz  = (const float*)d_in[7];
  const float* w_e1  = (const float*)d_in[8];
  const float* b_e1  = (const float*)d_in[9];
  const float* w_e2  = (const float*)d_in[10];
  const float* b_e2  = (const float*)d_in[11];
  const float* w_emu = (const float*)d_in[12];
  const float* b_emu = (const float*)d_in[13];
  const float* w_elv = (const float*)d_in[14];
  const float* b_elv = (const float*)d_in[15];
  const float* w_pr  = (const float*)d_in[16];
  const float* b_pr  = (const float*)d_in[17];
  const float* w_pmu = (const float*)d_in[18];
  const float* b_pmu = (const float*)d_in[19];
  const float* w_plv = (const float*)d_in[20];
  const float* b_plv = (const float*)d_in[21];
  const float* w_d1  = (const float*)d_in[22];
  const float* b_d1  = (const float*)d_in[23];
  const float* w_d2  = (const float*)d_in[24];
  const float* b_d2  = (const float*)d_in[25];
  const float* w_dmu = (const float*)d_in[26];
  const float* b_dmu = (const float*)d_in[27];
  const float* w_dlv = (const float*)d_in[28];
  const float* b_dlv = (const float*)d_in[29];
  const float* w_ih0 = (const float*)d_in[30];
  const float* w_hh0 = (const float*)d_in[31];
  const float* w_ih1 = (const float*)d_in[32];
  const float* w_hh1 = (const float*)d_in[33];

  char* base = (char*)d_ws;
  size_t off = 0;
  auto alloc = [&](size_t bytes)->char*{
    char* p = base + off;
    off = (off + bytes + 255) & ~(size_t)255;
    return p;
  };
  u16* xbf    = (u16*)alloc((size_t)4194304 * 2);
  u16* cb_px1 = (u16*)alloc((size_t)65536 * 2);
  u16* cb_px2 = (u16*)alloc((size_t)262144 * 2);
  u16* cb_pz  = (u16*)alloc((size_t)32768 * 2);
  u16* cb_e1  = (u16*)alloc((size_t)524288 * 2);
  u16* cb_e2  = (u16*)alloc((size_t)262144 * 2);
  u16* cb_emu = (u16*)alloc((size_t)32768 * 2);
  u16* cb_elv = (u16*)alloc((size_t)32768 * 2);
  u16* cb_pr  = (u16*)alloc((size_t)262144 * 2);
  u16* cb_pmu = (u16*)alloc((size_t)32768 * 2);
  u16* cb_plv = (u16*)alloc((size_t)32768 * 2);
  u16* cb_d1  = (u16*)alloc((size_t)524288 * 2);
  u16* cb_d2  = (u16*)alloc((size_t)262144 * 2);
  u16* cb_dmu = (u16*)alloc((size_t)65536 * 2);
  u16* cb_dlv = (u16*)alloc((size_t)65536 * 2);
  u16* cb_ih0 = (u16*)alloc((size_t)1572864 * 2);
  u16* cb_hh0 = (u16*)alloc((size_t)786432 * 2);
  u16* cb_ih1 = (u16*)alloc((size_t)786432 * 2);
  u16* cb_hh1 = (u16*)alloc((size_t)786432 * 2);
  u16* phiX   = (u16*)alloc((size_t)16777216 * 2);
  u16* phiX1  = (u16*)alloc((size_t)16777216 * 2);
  u16* h0a = (u16*)alloc((size_t)131072 * 2);
  u16* h0b = (u16*)alloc((size_t)131072 * 2);
  u16* h1a = (u16*)alloc((size_t)131072 * 2);
  u16* h1b = (u16*)alloc((size_t)131072 * 2);
  float* accf = (float*)alloc(256);

  // zero h state (4 contiguous buffers of 262144 B each)
  hipMemsetAsync(h0a, 0, (size_t)4 * 262144, stream);

  // plain converts: x, phi_x weights (row-major, prologue GEMMs)
  ConvMulti cm;
  cm.src[0] = x;     cm.dst[0] = xbf;    cm.n[0] = 4194304;
  cm.src[1] = w_px1; cm.dst[1] = cb_px1; cm.n[1] = 65536;
  cm.src[2] = w_px2; cm.dst[2] = cb_px2; cm.n[2] = 262144;
  cm.total = 4194304 + 65536 + 262144;
  k_convert<<<2048, 256, 0, stream>>>(cm);

  // repack the 16 recurrent-loop weights into fragment-linear bf16
  RepMulti rm; int ri = 0, rtot = 0;
  auto addr_ = [&](const float* s, u16* d, int N, int K){
    int lg = 0; while ((32 << lg) < K) ++lg;  // lg = log2(K/32)
    rm.src[ri] = s; rm.dst[ri] = d; rm.nk[ri] = N * K; rm.K[ri] = K; rm.lg[ri] = lg;
    rtot += N * K; ++ri;
  };
  addr_(w_pz,  cb_pz,  512, 64);
  addr_(w_e1,  cb_e1,  512, 1024);
  addr_(w_e2,  cb_e2,  512, 512);
  addr_(w_emu, cb_emu, 64, 512);
  addr_(w_elv, cb_elv, 64, 512);
  addr_(w_pr,  cb_pr,  512, 512);
  addr_(w_pmu, cb_pmu, 64, 512);
  addr_(w_plv, cb_plv, 64, 512);
  addr_(w_d1,  cb_d1,  512, 1024);
  addr_(w_d2,  cb_d2,  512, 512);
  addr_(w_dmu, cb_dmu, 128, 512);
  addr_(w_dlv, cb_dlv, 128, 512);
  addr_(w_ih0, cb_ih0, 1536, 1024);
  addr_(w_hh0, cb_hh0, 1536, 512);
  addr_(w_ih1, cb_ih1, 1536, 512);
  addr_(w_hh1, cb_hh1, 1536, 512);
  rm.total = rtot;
  k_repack<<<2048, 256, 0, stream>>>(rm);

  { // precompute phi_x over all T*B rows
    GemmDesc d1g;
    d1g.A = xbf; d1g.W = cb_px1; d1g.bias = b_px1; d1g.out = phiX1;
    d1g.lda = 128; d1g.ldw = 128; d1g.ldo = 512; d1g.N = 512; d1g.K = 128;
    k_gemm_pre<<<512 * 8, 256, 0, stream>>>(d1g);
    GemmDesc d2g;
    d2g.A = phiX1; d2g.W = cb_px2; d2g.bias = b_px2; d2g.out = phiX;
    d2g.lda = 512; d2g.ldw = 512; d2g.ldo = 512; d2g.N = 512; d2g.K = 512;
    k_gemm_pre<<<512 * 8, 256, 0, stream>>>(d2g);
  }

  Params prm;
  prm.phiX = phiX;
  prm.e1 = cb_e1; prm.pr = cb_pr; prm.e2 = cb_e2;
  prm.emu = cb_emu; prm.elv = cb_elv; prm.pmu = cb_pmu; prm.plv = cb_plv;
  prm.pz = cb_pz; prm.d1 = cb_d1; prm.ih0 = cb_ih0; prm.hh0 = cb_hh0;
  prm.ih1 = cb_ih1; prm.hh1 = cb_hh1; prm.d2 = cb_d2;
  prm.dmu = cb_dmu; prm.dlv = cb_dlv;
  prm.b_e1 = b_e1; prm.b_pr = b_pr; prm.b_e2 = b_e2;
  prm.b_emu = b_emu; prm.b_elv = b_elv; prm.b_pmu = b_pmu; prm.b_plv = b_plv;
  prm.b_pz = b_pz; prm.b_d1 = b_d1; prm.b_d2 = b_d2;
  prm.b_dmu = b_dmu; prm.b_dlv = b_dlv;
  prm.eps = eps; prm.x = x;
  prm.h0a = h0a; prm.h0b = h0b; prm.h1a = h1a; prm.h1b = h1b;
  prm.accf = accf;

  k_vrnn16<<<dim3(16), dim3(1024), 0, stream>>>(prm);
  k_final<<<dim3(1), dim3(64), 0, stream>>>(accf, (float*)d_out);
}